// Round 12
// baseline (105.339 us; speedup 1.0000x reference)
//
#include <hip/hip_runtime.h>
#include <hip/hip_bf16.h>
#include <cstddef>
#include <cstdint>

#define BATCH 4
#define CDIM 256
#define HW 4096
#define MCTX 1024
#define CTX 256
#define HEADS 8
#define DHEAD 64
#define INNER 512

typedef __attribute__((ext_vector_type(8))) short bf16x8;
typedef __attribute__((ext_vector_type(4))) float f32x4;
typedef __attribute__((ext_vector_type(16))) float f32x16;

static __device__ __forceinline__ ushort f2bf(float f) {
  __hip_bfloat16 h = __float2bfloat16(f);
  return *reinterpret_cast<ushort*>(&h);
}

// async global->LDS, 16B per lane. LDS dest is wave-uniform base + lane*16.
static __device__ __forceinline__ void gload16(const void* g, void* l) {
  __builtin_amdgcn_global_load_lds(
      (const __attribute__((address_space(1))) void*)(uintptr_t)g,
      (__attribute__((address_space(3))) void*)(uint32_t)(uintptr_t)l,
      16, 0, 0);
}

// ---------------------------------------------------------------------------
// LN over channels of x with layout transpose. x:[b,256,4096] -> xn:[b,4096,256]
// ---------------------------------------------------------------------------
static __device__ __forceinline__ void ln_x_body(
    const float* __restrict__ x, const float* __restrict__ g,
    const float* __restrict__ bta, float* __restrict__ xn,
    ushort* __restrict__ xnbf, int blk) {
  const int bi = blk / (HW / 32);
  const int n0 = (blk % (HW / 32)) * 32;
  __shared__ float xt[32][257];
  __shared__ float smu[32], srs[32];
  const int t = threadIdx.x;
  const float* xb = x + (size_t)bi * CDIM * HW;
  {
    const int cr = t >> 3;            // c within pass (32 per pass)
    const int n4 = (t & 7) * 4;       // 8 lanes x float4 cover 32 n
    #pragma unroll
    for (int pass = 0; pass < 8; ++pass) {
      const int c = pass * 32 + cr;
      float4 v = *(const float4*)(xb + (size_t)c * HW + n0 + n4);
      xt[n4 + 0][c] = v.x; xt[n4 + 1][c] = v.y;
      xt[n4 + 2][c] = v.z; xt[n4 + 3][c] = v.w;
    }
  }
  __syncthreads();
  const int col = t >> 3, j = t & 7;
  float s = 0.f, ss = 0.f;
  #pragma unroll
  for (int c = j; c < CDIM; c += 8) {
    float v = xt[col][c];
    s += v; ss += v * v;
  }
  #pragma unroll
  for (int off = 1; off < 8; off <<= 1) {
    s += __shfl_xor(s, off);
    ss += __shfl_xor(ss, off);
  }
  if (j == 0) {
    float mu = s * (1.f / CDIM);
    smu[col] = mu;
    srs[col] = rsqrtf(ss * (1.f / CDIM) - mu * mu + 1e-5f);
  }
  __syncthreads();
  const float gv = g[t], bvv = bta[t];
  float* xnb = xn + ((size_t)bi * HW + n0) * CDIM;
  ushort* xbb = xnbf + ((size_t)bi * HW + n0) * CDIM;
  #pragma unroll 4
  for (int n = 0; n < 32; ++n) {
    float val = (xt[n][t] - smu[n]) * srs[n] * gv + bvv;
    xnb[(size_t)n * CDIM + t] = val;
    xbb[(size_t)n * CDIM + t] = f2bf(val);
  }
}

// ---------------------------------------------------------------------------
// LN y rows -> bf16. 4 waves per block, one row each.
// ---------------------------------------------------------------------------
static __device__ __forceinline__ void ln_y_body(
    const float* __restrict__ y, const float* __restrict__ g,
    const float* __restrict__ bta, ushort* __restrict__ ynbf, int blk) {
  const int row = blk * 4 + (threadIdx.x >> 6);
  const int t = threadIdx.x & 63;
  float4 v = ((const float4*)(y + (size_t)row * CTX))[t];
  float s = v.x + v.y + v.z + v.w;
  float ss = v.x * v.x + v.y * v.y + v.z * v.z + v.w * v.w;
  #pragma unroll
  for (int off = 1; off < 64; off <<= 1) {
    s += __shfl_xor(s, off);
    ss += __shfl_xor(ss, off);
  }
  float mu = s * (1.f / CTX);
  float rs = rsqrtf(ss * (1.f / CTX) - mu * mu + 1e-5f);
  float4 gv = ((const float4*)g)[t];
  float4 b4 = ((const float4*)bta)[t];
  ushort4 ob;
  ob.x = f2bf((v.x - mu) * rs * gv.x + b4.x);
  ob.y = f2bf((v.y - mu) * rs * gv.y + b4.y);
  ob.z = f2bf((v.z - mu) * rs * gv.z + b4.z);
  ob.w = f2bf((v.w - mu) * rs * gv.w + b4.w);
  *(ushort4*)(ynbf + (size_t)row * CTX + t * 4) = ob;
}

// ---------------------------------------------------------------------------
// Weight prep: W [K][N] fp32 -> Wt [N][K] bf16 (64x64 LDS transpose tiles).
// ---------------------------------------------------------------------------
static __device__ __forceinline__ void wprep_body(
    const float* __restrict__ W, ushort* __restrict__ Wt, int K, int N,
    int bx, int by) {
  __shared__ ushort T[64][65];
  const int k0 = by * 64, n0 = bx * 64;
  const int t = threadIdx.x;
  #pragma unroll
  for (int rr = 0; rr < 4; ++rr) {
    int row = rr * 16 + (t >> 4);          // k
    int c = (t & 15) * 4;                  // n
    float4 wv = *(const float4*)(W + (size_t)(k0 + row) * N + n0 + c);
    T[row][c + 0] = f2bf(wv.x); T[row][c + 1] = f2bf(wv.y);
    T[row][c + 2] = f2bf(wv.z); T[row][c + 3] = f2bf(wv.w);
  }
  __syncthreads();
  #pragma unroll
  for (int rr = 0; rr < 4; ++rr) {
    int nrow = rr * 16 + (t >> 4);
    int kc = (t & 15) * 4;
    ushort4 o;
    o.x = T[kc + 0][nrow]; o.y = T[kc + 1][nrow];
    o.z = T[kc + 2][nrow]; o.w = T[kc + 3][nrow];
    *(ushort4*)(Wt + (size_t)(n0 + nrow) * K + k0 + kc) = o;
  }
}

// ---------------------------------------------------------------------------
// MERGED PREP: ln_x (512 blocks, longest, first) + ln_y (1024) + wprep (128).
// ---------------------------------------------------------------------------
__global__ __launch_bounds__(256) void prep_kernel(
    const float* __restrict__ x, const float* __restrict__ ln_xg,
    const float* __restrict__ ln_xb, float* __restrict__ xn,
    ushort* __restrict__ xnbf,
    const float* __restrict__ y, const float* __restrict__ ln_yg,
    const float* __restrict__ ln_yb, ushort* __restrict__ ynbf,
    const float* __restrict__ Wq, const float* __restrict__ Wk,
    const float* __restrict__ Wv, const float* __restrict__ Wo,
    ushort* __restrict__ wtq, ushort* __restrict__ wtk,
    ushort* __restrict__ wtv, ushort* __restrict__ wto) {
  const int id = blockIdx.x;
  if (id < 512) {
    ln_x_body(x, ln_xg, ln_xb, xn, xnbf, id);
  } else if (id < 1536) {
    ln_y_body(y, ln_yg, ln_yb, ynbf, id - 512);
  } else {
    const int r = id - 1536;                 // 0..127
    const int z = r >> 5, rem = r & 31;
    const int bx = rem & 7, by = rem >> 3;
    if (z < 3) {
      const float* W = (z == 0) ? Wq : (z == 1) ? Wk : Wv;
      ushort* Wt = (z == 0) ? wtq : (z == 1) ? wtk : wtv;
      wprep_body(W, Wt, 256, 512, bx, by);
    } else {
      wprep_body(Wo, wto, 512, 256, bx & 3, by * 2 + (bx >> 2));
    }
  }
}

// ---------------------------------------------------------------------------
// bf16 MFMA GEMM body: C[M][N] = A[M][K] @ Bt[N][K]^T, 128x128 tile, BK=64,
// 4 waves (2x2), each wave 64x64. global_load_lds staging, rule-#21 swizzle.
// Optional vt_out: write C transposed per-head ([b*h][d][m]).
// ---------------------------------------------------------------------------
template <bool F32_RES_OUT>
static __device__ __forceinline__ void gemm_body(
    const ushort* __restrict__ A, const ushort* __restrict__ Bt,
    const float* __restrict__ bias, const float* __restrict__ res,
    void* __restrict__ Cout, ushort* __restrict__ vt_out,
    int M, int N, int K, float scale, int m0, int n0) {
  __shared__ ushort As[128 * 64];   // linear, 16 KiB
  __shared__ ushort Bs[128 * 64];
  const int t = threadIdx.x;
  const int l = t & 63, w = t >> 6;
  const int lq = l & 15, lg = l >> 4;
  const int wr = w >> 1, wc = w & 1;
  f32x4 acc[4][4];
  #pragma unroll
  for (int mt = 0; mt < 4; ++mt)
    #pragma unroll
    for (int nt = 0; nt < 4; ++nt)
      #pragma unroll
      for (int e = 0; e < 4; ++e) acc[mt][nt][e] = 0.f;
  const int srow = w * 8 + (l >> 3);
  const int scol = ((l & 7) ^ (l >> 3)) * 8;
  const ushort* pA = A + (size_t)(m0 + srow) * K + scol;
  const ushort* pB = Bt + (size_t)(n0 + srow) * K + scol;
  const int dbase = w * 512;               // shorts (wave chunk base)
  for (int k0 = 0; k0 < K; k0 += 64) {
    if (k0) __syncthreads();               // prior reads done before overwrite
    #pragma unroll
    for (int i = 0; i < 4; ++i) {
      gload16(pA + (size_t)(i * 32) * K + k0, &As[i * 2048 + dbase]);
      gload16(pB + (size_t)(i * 32) * K + k0, &Bs[i * 2048 + dbase]);
    }
    __syncthreads();                       // drains vmcnt -> tile visible
    #pragma unroll
    for (int ks = 0; ks < 2; ++ks) {
      bf16x8 af[4], bfr[4];
      #pragma unroll
      for (int mt = 0; mt < 4; ++mt) {
        const int R = wr * 64 + mt * 16 + lq;
        af[mt] = *(const bf16x8*)(
            &As[R * 64 + ((ks * 32 + lg * 8) ^ ((R & 7) * 8))]);
      }
      #pragma unroll
      for (int nt = 0; nt < 4; ++nt) {
        const int R = wc * 64 + nt * 16 + lq;
        bfr[nt] = *(const bf16x8*)(
            &Bs[R * 64 + ((ks * 32 + lg * 8) ^ ((R & 7) * 8))]);
      }
      #pragma unroll
      for (int mt = 0; mt < 4; ++mt)
        #pragma unroll
        for (int nt = 0; nt < 4; ++nt)
          acc[mt][nt] = __builtin_amdgcn_mfma_f32_16x16x32_bf16(
              af[mt], bfr[nt], acc[mt][nt], 0, 0, 0);
    }
  }
  #pragma unroll
  for (int nt = 0; nt < 4; ++nt) {
    const int colc = n0 + wc * 64 + nt * 16 + lq;
    const float bcol = bias ? bias[colc] : 0.f;
    #pragma unroll
    for (int mt = 0; mt < 4; ++mt) {
      #pragma unroll
      for (int i = 0; i < 4; ++i) {
        const size_t row = (size_t)(m0 + wr * 64 + mt * 16 + lg * 4 + i);
        float v = acc[mt][nt][i] * scale + bcol;
        if (vt_out) {
          // transposed per-head: vt[(bi*8+h)*64 + d][m], h=colc>>6, d=colc&63
          vt_out[(size_t)((((row >> 10) * 8 + (colc >> 6)) << 6) + (colc & 63)) * MCTX
                 + (row & (MCTX - 1))] = f2bf(v);
        } else if (F32_RES_OUT) {
          ((float*)Cout)[row * N + colc] = v + res[row * N + colc];
        } else {
          ((ushort*)Cout)[row * N + colc] = f2bf(v);
        }
      }
    }
  }
}

// ---------------------------------------------------------------------------
// MERGED PROJECTIONS: Q (512) + K (128) + V (128, transposed-epilogue).
// ---------------------------------------------------------------------------
__global__ __launch_bounds__(256) void qkv_kernel(
    const ushort* __restrict__ xnbf, const ushort* __restrict__ ynbf,
    const ushort* __restrict__ wtq, const ushort* __restrict__ wtk,
    const ushort* __restrict__ wtv, const float* __restrict__ bv,
    ushort* __restrict__ qbf, ushort* __restrict__ kbf,
    ushort* __restrict__ vtb) {
  const int id = blockIdx.x;
  if (id < 512) {
    // q = (xn @ Wq) * 0.125 * log2(e)  (softmax runs in exp2 domain)
    gemm_body<false>(xnbf, wtq, nullptr, nullptr, qbf, nullptr,
                     16384, 512, 256, 0.1803368801111204f,
                     (id >> 2) * 128, (id & 3) * 128);
  } else if (id < 640) {
    const int i2 = id - 512;
    gemm_body<false>(ynbf, wtk, nullptr, nullptr, kbf, nullptr,
                     4096, 512, 256, 1.f, (i2 >> 2) * 128, (i2 & 3) * 128);
  } else {
    const int i2 = id - 640;
    gemm_body<false>(ynbf, wtv, bv, nullptr, nullptr, vtb,
                     4096, 512, 256, 1.f, (i2 >> 2) * 128, (i2 & 3) * 128);
  }
}

// ---------------------------------------------------------------------------
// AO GEMM + residual: out[16384][256] = ao @ Wo + bo + xn.  64x128 tile,
// BK=64, 4 waves (2x2), each wave 32x64 — 512 blocks = 2/CU (the old
// 128x128 grid was 256 blocks = 1/CU, latency-bound on the 32MB f32
// res-read/out-write epilogue). Same staging/swizzle as gemm_body.
// ---------------------------------------------------------------------------
__global__ __launch_bounds__(256) void ao_gemm_kernel(
    const ushort* __restrict__ A, const ushort* __restrict__ Bt,
    const float* __restrict__ bias, const float* __restrict__ res,
    float* __restrict__ out) {
  __shared__ ushort As[64 * 64];    // 8 KiB
  __shared__ ushort Bs[128 * 64];   // 16 KiB
  const int t = threadIdx.x;
  const int l = t & 63, w = t >> 6;
  const int lq = l & 15, lg = l >> 4;
  const int wr = w >> 1, wc = w & 1;
  const int m0 = blockIdx.y * 64, n0 = blockIdx.x * 128;
  f32x4 acc[2][4];
  #pragma unroll
  for (int mt = 0; mt < 2; ++mt)
    #pragma unroll
    for (int nt = 0; nt < 4; ++nt)
      #pragma unroll
      for (int e = 0; e < 4; ++e) acc[mt][nt][e] = 0.f;
  const int srow = w * 8 + (l >> 3);
  const int scol = ((l & 7) ^ (l >> 3)) * 8;
  const ushort* pA = A + (size_t)(m0 + srow) * INNER + scol;
  const ushort* pB = Bt + (size_t)(n0 + srow) * INNER + scol;
  const int dbase = w * 512;
  for (int k0 = 0; k0 < INNER; k0 += 64) {
    if (k0) __syncthreads();
    #pragma unroll
    for (int i = 0; i < 2; ++i)
      gload16(pA + (size_t)(i * 32) * INNER + k0, &As[i * 2048 + dbase]);
    #pragma unroll
    for (int i = 0; i < 4; ++i)
      gload16(pB + (size_t)(i * 32) * INNER + k0, &Bs[i * 2048 + dbase]);
    __syncthreads();
    #pragma unroll
    for (int ks = 0; ks < 2; ++ks) {
      bf16x8 af[2], bfr[4];
      #pragma unroll
      for (int mt = 0; mt < 2; ++mt) {
        const int R = wr * 32 + mt * 16 + lq;
        af[mt] = *(const bf16x8*)(
            &As[R * 64 + ((ks * 32 + lg * 8) ^ ((R & 7) * 8))]);
      }
      #pragma unroll
      for (int nt = 0; nt < 4; ++nt) {
        const int R = wc * 64 + nt * 16 + lq;
        bfr[nt] = *(const bf16x8*)(
            &Bs[R * 64 + ((ks * 32 + lg * 8) ^ ((R & 7) * 8))]);
      }
      #pragma unroll
      for (int mt = 0; mt < 2; ++mt)
        #pragma unroll
        for (int nt = 0; nt < 4; ++nt)
          acc[mt][nt] = __builtin_amdgcn_mfma_f32_16x16x32_bf16(
              af[mt], bfr[nt], acc[mt][nt], 0, 0, 0);
    }
  }
  #pragma unroll
  for (int nt = 0; nt < 4; ++nt) {
    const int colc = n0 + wc * 64 + nt * 16 + lq;
    const float bcol = bias[colc];
    #pragma unroll
    for (int mt = 0; mt < 2; ++mt) {
      #pragma unroll
      for (int i = 0; i < 4; ++i) {
        const size_t row = (size_t)(m0 + wr * 32 + mt * 16 + lg * 4 + i);
        out[row * CDIM + colc] = acc[mt][nt][i] + bcol + res[row * CDIM + colc];
      }
    }
  }
}

// ---------------------------------------------------------------------------
// Flash attention, bf16 MFMA, 32x32 tiles + in-register P via permlane swap,
// now TWO 32x32 q-groups per wave (64 q-rows): each K/V LDS fragment read is
// amortized over both groups (LDS-pipe work halves — it was the largest
// per-CU floor: 16w x 17 b128 x 12cy x 16t ~ 52k cy), and group-1's QK MFMAs
// overlap group-0's softmax VALU inside the wave. 8 waves x 64 rows = 512
// q-rows/block; 256 blocks = 1 block/CU at (512,2) -> 256-VGPR budget
// (live set ~210; r3's spill was at the 128 cap, not here — watch WRITE_SIZE).
// QK^T C-layout (m74/m101): col=q=lane&31, row=key=(reg&3)+8*(reg>>2)+4*hi.
// Softmax in-lane + one shfl_xor(32); exp2 domain; defer-max THR=8.
// P -> PV A-frags via v_permlane32_swap_b32 ([Sa,Sb,Da,Db] both halves).
// LEDGER: 4-wave blocks -13% (r5); gload_lds K/V in attn -13% (r5); K=16 PV
// -7% (r8); intra-tile reorder flat (r4); 16x16+LDS-P = 61-62us (r7/r9);
// 32x32 1-group = 56.5us (r10/r11).
// ---------------------------------------------------------------------------
__global__ __launch_bounds__(512, 2) void attn_mfma(
    const ushort* __restrict__ q, const ushort* __restrict__ k,
    const ushort* __restrict__ vt, ushort* __restrict__ ao) {
  // XCD-aware swizzle (bijective: 256 = 8 * 32)
  const int bid = blockIdx.x + 8 * (blockIdx.y + 8 * blockIdx.z);
  const int swz = (bid & 7) * 32 + (bid >> 3);
  const int bi = swz >> 6;
  const int h = (swz >> 3) & 7;
  const int n0 = (swz & 7) * 512;
  const int tile0 = (bid & 3) << 2;        // phase stagger: 0,4,8,12
  __shared__ ushort Ks[2][64 * 64];
  __shared__ ushort Vs[2][64 * 64];
  const int t = threadIdx.x;
  const int l = t & 63, w = t >> 6;
  const int lq32 = l & 31, hi = l >> 5;

  // Q fragments per group (B operand of QK: B[k=d][col=q], k=hi*8+e per step)
  bf16x8 bq0[4], bq1[4];
  {
    const size_t qr0 = (size_t)(bi * HW + n0 + w * 64 + lq32);
    const size_t qr1 = qr0 + 32;
    #pragma unroll
    for (int ds = 0; ds < 4; ++ds) {
      bq0[ds] = *(const bf16x8*)(q + qr0 * INNER + h * DHEAD + ds * 16 + hi * 8);
      bq1[ds] = *(const bf16x8*)(q + qr1 * INNER + h * DHEAD + ds * 16 + hi * 8);
    }
  }

  float m_run0 = -1e30f, l_run0 = 0.f, m_run1 = -1e30f, l_run1 = 0.f;
  f32x16 oacc0[2], oacc1[2];
  #pragma unroll
  for (int dt = 0; dt < 2; ++dt)
    #pragma unroll
    for (int e = 0; e < 16; ++e) { oacc0[dt][e] = 0.f; oacc1[dt][e] = 0.f; }

  // staging: 64x64 bf16 tile = 512 uint4; 512 threads -> 1 uint4 each
  const int rr = t >> 3, cc = (t & 7) * 8;
  const ushort* kptr = k + (size_t)(bi * MCTX + rr) * INNER + h * DHEAD + cc;
  const ushort* vptr = vt + (size_t)((bi * HEADS + h) * 64 + rr) * MCTX + cc;
  const int sidx = (rr * 64 + cc) ^ ((rr & 7) << 3);

  {  // stage first tile (tile0) into buffer 0
    const int ms = tile0 << 6;
    uint4 k0v = *(const uint4*)(kptr + (size_t)ms * INNER);
    uint4 v0v = *(const uint4*)(vptr + ms);
    *(uint4*)(&Ks[0][sidx]) = k0v;
    *(uint4*)(&Vs[0][sidx]) = v0v;
  }
  __syncthreads();

  // softmax for one q-group: scores -> P A-frags (registers), online max/sum.
  auto softmax_group = [&](f32x16 (&scg)[2], float& mr, float& lr,
                           f32x16 (&oa)[2], bf16x8 (&paf)[4]) {
    f32x16 mx;
    #pragma unroll
    for (int e = 0; e < 16; ++e) mx[e] = fmaxf(scg[0][e], scg[1][e]);
    #pragma unroll
    for (int e = 0; e < 8; ++e) mx[e] = fmaxf(mx[e], mx[e + 8]);
    #pragma unroll
    for (int e = 0; e < 4; ++e) mx[e] = fmaxf(mx[e], mx[e + 4]);
    float mloc = fmaxf(fmaxf(mx[0], mx[1]), fmaxf(mx[2], mx[3]));
    mloc = fmaxf(mloc, __shfl_xor(mloc, 32));
    if (!__all((int)(mloc - mr <= 8.f))) {
      const float mnew = fmaxf(mr, mloc);
      const float corr = __builtin_amdgcn_exp2f(mr - mnew);
      lr *= corr;
      mr = mnew;
      #pragma unroll
      for (int r = 0; r < 16; ++r) {
        const int qrow = (r & 3) + 8 * (r >> 2) + 4 * hi;
        float ci = __shfl(corr, qrow);
        oa[0][r] *= ci; oa[1][r] *= ci;
      }
    }
    #pragma unroll
    for (int kt = 0; kt < 2; ++kt)
      #pragma unroll
      for (int e = 0; e < 16; ++e)
        scg[kt][e] = __builtin_amdgcn_exp2f(scg[kt][e] - mr);
    f32x16 s16;
    #pragma unroll
    for (int e = 0; e < 16; ++e) s16[e] = scg[0][e] + scg[1][e];
    #pragma unroll
    for (int e = 0; e < 8; ++e) s16[e] += s16[e + 8];
    #pragma unroll
    for (int e = 0; e < 4; ++e) s16[e] += s16[e + 4];
    float psum = (s16[0] + s16[1]) + (s16[2] + s16[3]);
    psum += __shfl_xor(psum, 32);
    lr += psum;
    #pragma unroll
    for (int kt = 0; kt < 2; ++kt) {
      uint wa[4], wb[4];
      #pragma unroll
      for (int r4 = 0; r4 < 4; ++r4) {
        wa[r4] = (uint)f2bf(scg[kt][4 * r4]) | ((uint)f2bf(scg[kt][4 * r4 + 1]) << 16);
        wb[r4] = (uint)f2bf(scg[kt][4 * r4 + 2]) | ((uint)f2bf(scg[kt][4 * r4 + 3]) << 16);
      }
      #pragma unroll
      for (int p2 = 0; p2 < 2; ++p2) {
        uint Sa = wa[2 * p2], Da = wa[2 * p2 + 1];
        uint Sb = wb[2 * p2], Db = wb[2 * p2 + 1];
        asm volatile("v_permlane32_swap_b32 %0, %1" : "+v"(Da), "+v"(Sa));
        asm volatile("v_permlane32_swap_b32 %0, %1" : "+v"(Db), "+v"(Sb));
        uint4 fr;
        fr.x = Sa; fr.y = Sb; fr.z = Da; fr.w = Db;
        paf[kt * 2 + p2] = *reinterpret_cast<bf16x8*>(&fr);
      }
    }
  };

  #pragma unroll 2
  for (int it = 0; it < 16; ++it) {
    const int buf = it & 1;
    const bool more = (it + 1) < 16;
    const int mnext = ((tile0 + it + 1) & 15) << 6;
    uint4 kpre{}, vpre{};
    if (more) {  // prefetch next tile; staged to LDS between sm0 and sm1
      kpre = *(const uint4*)(kptr + (size_t)mnext * INNER);
      vpre = *(const uint4*)(vptr + mnext);
    }
    // QK^T both groups: ak shared (one LDS read serves 64 q-rows)
    f32x16 sc0[2], sc1[2];
    #pragma unroll
    for (int kt = 0; kt < 2; ++kt)
      #pragma unroll
      for (int e = 0; e < 16; ++e) { sc0[kt][e] = 0.f; sc1[kt][e] = 0.f; }
    __builtin_amdgcn_s_setprio(1);
    #pragma unroll
    for (int kt = 0; kt < 2; ++kt) {
      #pragma unroll
      for (int ds = 0; ds < 4; ++ds) {
        const int krow = kt * 32 + lq32;
        bf16x8 ak = *(const bf16x8*)(
            &Ks[buf][(krow * 64 + ds * 16 + hi * 8) ^ ((krow & 7) << 3)]);
        sc0[kt] = __builtin_amdgcn_mfma_f32_32x32x16_bf16(ak, bq0[ds], sc0[kt], 0, 0, 0);
        sc1[kt] = __builtin_amdgcn_mfma_f32_32x32x16_bf16(ak, bq1[ds], sc1[kt], 0, 0, 0);
      }
    }
    __builtin_amdgcn_s_setprio(0);
    bf16x8 pa0[4], pa1[4];
    // group 0 softmax (P stays in registers)
    softmax_group(sc0, m_run0, l_run0, oacc0, pa0);
    // stage next tile (buf^1 last read before previous barrier); drains
    // during sm(g1) + PV
    if (more) {
      *(uint4*)(&Ks[buf ^ 1][sidx]) = kpre;
      *(uint4*)(&Vs[buf ^ 1][sidx]) = vpre;
    }
    // group 1 softmax
    softmax_group(sc1, m_run1, l_run1, oacc1, pa1);
    // PV both groups: vb shared (one LDS read serves 64 q-rows)
    __builtin_amdgcn_s_setprio(1);
    #pragma unroll
    for (int dt = 0; dt < 2; ++dt) {
      const int vrow = dt * 32 + lq32;
      #pragma unroll
      for (int kt16 = 0; kt16 < 4; ++kt16) {
        bf16x8 vb = *(const bf16x8*)(
            &Vs[buf][(vrow * 64 + kt16 * 16 + hi * 8) ^ ((vrow & 7) << 3)]);
        oacc0[dt] = __builtin_amdgcn_mfma_f32_32x32x16_bf16(pa0[kt16], vb, oacc0[dt], 0, 0, 0);
        oacc1[dt] = __builtin_amdgcn_mfma_f32_32x32x16_bf16(pa1[kt16], vb, oacc1[dt], 0, 0, 0);
      }
    }
    __builtin_amdgcn_s_setprio(0);
    __syncthreads();
  }
  {
    const float rl0 = 1.f / l_run0, rl1 = 1.f / l_run1;
    #pragma unroll
    for (int r = 0; r < 16; ++r) {
      const int qrow = (r & 3) + 8 * (r >> 2) + 4 * hi;
      const float li0 = __shfl(rl0, qrow);
      const float li1 = __shfl(rl1, qrow);
      const size_t row0 = (size_t)(bi * HW + n0 + w * 64 + qrow);
      const size_t row1 = row0 + 32;
      ao[row0 * INNER + h * DHEAD + lq32] = f2bf(oacc0[0][r] * li0);
      ao[row0 * INNER + h * DHEAD + 32 + lq32] = f2bf(oacc0[1][r] * li0);
      ao[row1 * INNER + h * DHEAD + lq32] = f2bf(oacc1[0][r] * li1);
      ao[row1 * INNER + h * DHEAD + 32 + lq32] = f2bf(oacc1[1][r] * li1);
    }
  }
}

// ---------------------------------------------------------------------------
extern "C" void kernel_launch(void* const* d_in, const int* in_sizes, int n_in,
                              void* d_out, int out_size, void* d_ws, size_t ws_size,
                              hipStream_t stream) {
  const float* x     = (const float*)d_in[0];
  const float* y     = (const float*)d_in[1];
  const float* ln_xg = (const float*)d_in[2];
  const float* ln_xb = (const float*)d_in[3];
  const float* ln_yg = (const float*)d_in[4];
  const float* ln_yb = (const float*)d_in[5];
  const float* Wq    = (const float*)d_in[6];
  const float* Wk    = (const float*)d_in[7];
  const float* Wv    = (const float*)d_in[8];
  const float* bv    = (const float*)d_in[9];
  const float* Wo    = (const float*)d_in[10];
  const float* bo    = (const float*)d_in[11];
  float* out = (float*)d_out;

  char* p = (char*)d_ws;
  float*  xn   = (float*)p;  p += (size_t)16384 * 256 * 4;
  ushort* xnbf = (ushort*)p; p += (size_t)16384 * 256 * 2;
  ushort* ynbf = (ushort*)p; p += (size_t)4096 * 256 * 2;
  ushort* wtq  = (ushort*)p; p += (size_t)512 * 256 * 2;
  ushort* wtk  = (ushort*)p; p += (size_t)512 * 256 * 2;
  ushort* wtv  = (ushort*)p; p += (size_t)512 * 256 * 2;
  ushort* wto  = (ushort*)p; p += (size_t)256 * 512 * 2;
  ushort* qbf  = (ushort*)p; p += (size_t)16384 * 512 * 2;
  ushort* kbf  = (ushort*)p; p += (size_t)4096 * 512 * 2;
  ushort* vtb  = (ushort*)p; p += (size_t)4096 * 512 * 2;
  ushort* aobf = (ushort*)p; p += (size_t)16384 * 512 * 2;

  // 1) all preprocessing in one launch (ln_x first: longest)
  prep_kernel<<<dim3(512 + 1024 + 128), 256, 0, stream>>>(
      x, ln_xg, ln_xb, xn, xnbf, y, ln_yg, ln_yb, ynbf,
      Wq, Wk, Wv, Wo, wtq, wtk, wtv, wto);
  // 2) Q + K + V projections in one launch (V written transposed per-head)
  qkv_kernel<<<dim3(768), 256, 0, stream>>>(
      xnbf, ynbf, wtq, wtk, wtv, bv, qbf, kbf, vtb);
  // 3) attention (512 q-rows/block, 2 groups/wave)
  attn_mfma<<<dim3(HW / 512, HEADS, BATCH), 512, 0, stream>>>(qbf, kbf, vtb, aobf);
  // 4) out = ao @ Wo + bo + xn  (64x128 tiles -> 512 blocks, 2/CU)
  ao_gemm_kernel<<<dim3(2, 256), 256, 0, stream>>>(aobf, wto, bo, xn, out);
}

// Round 13
// 104.227 us; speedup vs baseline: 1.0107x; 1.0107x over previous
//
#include <hip/hip_runtime.h>
#include <hip/hip_bf16.h>
#include <cstddef>
#include <cstdint>

#define BATCH 4
#define CDIM 256
#define HW 4096
#define MCTX 1024
#define CTX 256
#define HEADS 8
#define DHEAD 64
#define INNER 512

typedef __attribute__((ext_vector_type(8))) short bf16x8;
typedef __attribute__((ext_vector_type(4))) float f32x4;
typedef __attribute__((ext_vector_type(16))) float f32x16;

static __device__ __forceinline__ ushort f2bf(float f) {
  __hip_bfloat16 h = __float2bfloat16(f);
  return *reinterpret_cast<ushort*>(&h);
}

// async global->LDS, 16B per lane. LDS dest is wave-uniform base + lane*16.
static __device__ __forceinline__ void gload16(const void* g, void* l) {
  __builtin_amdgcn_global_load_lds(
      (const __attribute__((address_space(1))) void*)(uintptr_t)g,
      (__attribute__((address_space(3))) void*)(uint32_t)(uintptr_t)l,
      16, 0, 0);
}

// ---------------------------------------------------------------------------
// LN over channels of x with layout transpose. x:[b,256,4096] -> xn:[b,4096,256]
// ---------------------------------------------------------------------------
static __device__ __forceinline__ void ln_x_body(
    const float* __restrict__ x, const float* __restrict__ g,
    const float* __restrict__ bta, float* __restrict__ xn,
    ushort* __restrict__ xnbf, int blk) {
  const int bi = blk / (HW / 32);
  const int n0 = (blk % (HW / 32)) * 32;
  __shared__ float xt[32][257];
  __shared__ float smu[32], srs[32];
  const int t = threadIdx.x;
  const float* xb = x + (size_t)bi * CDIM * HW;
  {
    const int cr = t >> 3;            // c within pass (32 per pass)
    const int n4 = (t & 7) * 4;       // 8 lanes x float4 cover 32 n
    #pragma unroll
    for (int pass = 0; pass < 8; ++pass) {
      const int c = pass * 32 + cr;
      float4 v = *(const float4*)(xb + (size_t)c * HW + n0 + n4);
      xt[n4 + 0][c] = v.x; xt[n4 + 1][c] = v.y;
      xt[n4 + 2][c] = v.z; xt[n4 + 3][c] = v.w;
    }
  }
  __syncthreads();
  const int col = t >> 3, j = t & 7;
  float s = 0.f, ss = 0.f;
  #pragma unroll
  for (int c = j; c < CDIM; c += 8) {
    float v = xt[col][c];
    s += v; ss += v * v;
  }
  #pragma unroll
  for (int off = 1; off < 8; off <<= 1) {
    s += __shfl_xor(s, off);
    ss += __shfl_xor(ss, off);
  }
  if (j == 0) {
    float mu = s * (1.f / CDIM);
    smu[col] = mu;
    srs[col] = rsqrtf(ss * (1.f / CDIM) - mu * mu + 1e-5f);
  }
  __syncthreads();
  const float gv = g[t], bvv = bta[t];
  float* xnb = xn + ((size_t)bi * HW + n0) * CDIM;
  ushort* xbb = xnbf + ((size_t)bi * HW + n0) * CDIM;
  #pragma unroll 4
  for (int n = 0; n < 32; ++n) {
    float val = (xt[n][t] - smu[n]) * srs[n] * gv + bvv;
    xnb[(size_t)n * CDIM + t] = val;
    xbb[(size_t)n * CDIM + t] = f2bf(val);
  }
}

// ---------------------------------------------------------------------------
// LN y rows -> bf16. 4 waves per block, one row each.
// ---------------------------------------------------------------------------
static __device__ __forceinline__ void ln_y_body(
    const float* __restrict__ y, const float* __restrict__ g,
    const float* __restrict__ bta, ushort* __restrict__ ynbf, int blk) {
  const int row = blk * 4 + (threadIdx.x >> 6);
  const int t = threadIdx.x & 63;
  float4 v = ((const float4*)(y + (size_t)row * CTX))[t];
  float s = v.x + v.y + v.z + v.w;
  float ss = v.x * v.x + v.y * v.y + v.z * v.z + v.w * v.w;
  #pragma unroll
  for (int off = 1; off < 64; off <<= 1) {
    s += __shfl_xor(s, off);
    ss += __shfl_xor(ss, off);
  }
  float mu = s * (1.f / CTX);
  float rs = rsqrtf(ss * (1.f / CTX) - mu * mu + 1e-5f);
  float4 gv = ((const float4*)g)[t];
  float4 b4 = ((const float4*)bta)[t];
  ushort4 ob;
  ob.x = f2bf((v.x - mu) * rs * gv.x + b4.x);
  ob.y = f2bf((v.y - mu) * rs * gv.y + b4.y);
  ob.z = f2bf((v.z - mu) * rs * gv.z + b4.z);
  ob.w = f2bf((v.w - mu) * rs * gv.w + b4.w);
  *(ushort4*)(ynbf + (size_t)row * CTX + t * 4) = ob;
}

// ---------------------------------------------------------------------------
// Weight prep: W [K][N] fp32 -> Wt [N][K] bf16 (64x64 LDS transpose tiles).
// ---------------------------------------------------------------------------
static __device__ __forceinline__ void wprep_body(
    const float* __restrict__ W, ushort* __restrict__ Wt, int K, int N,
    int bx, int by) {
  __shared__ ushort T[64][65];
  const int k0 = by * 64, n0 = bx * 64;
  const int t = threadIdx.x;
  #pragma unroll
  for (int rr = 0; rr < 4; ++rr) {
    int row = rr * 16 + (t >> 4);          // k
    int c = (t & 15) * 4;                  // n
    float4 wv = *(const float4*)(W + (size_t)(k0 + row) * N + n0 + c);
    T[row][c + 0] = f2bf(wv.x); T[row][c + 1] = f2bf(wv.y);
    T[row][c + 2] = f2bf(wv.z); T[row][c + 3] = f2bf(wv.w);
  }
  __syncthreads();
  #pragma unroll
  for (int rr = 0; rr < 4; ++rr) {
    int nrow = rr * 16 + (t >> 4);
    int kc = (t & 15) * 4;
    ushort4 o;
    o.x = T[kc + 0][nrow]; o.y = T[kc + 1][nrow];
    o.z = T[kc + 2][nrow]; o.w = T[kc + 3][nrow];
    *(ushort4*)(Wt + (size_t)(n0 + nrow) * K + k0 + kc) = o;
  }
}

// ---------------------------------------------------------------------------
// MERGED PREP: ln_x (512 blocks, longest, first) + ln_y (1024) + wprep (128).
// ---------------------------------------------------------------------------
__global__ __launch_bounds__(256) void prep_kernel(
    const float* __restrict__ x, const float* __restrict__ ln_xg,
    const float* __restrict__ ln_xb, float* __restrict__ xn,
    ushort* __restrict__ xnbf,
    const float* __restrict__ y, const float* __restrict__ ln_yg,
    const float* __restrict__ ln_yb, ushort* __restrict__ ynbf,
    const float* __restrict__ Wq, const float* __restrict__ Wk,
    const float* __restrict__ Wv, const float* __restrict__ Wo,
    ushort* __restrict__ wtq, ushort* __restrict__ wtk,
    ushort* __restrict__ wtv, ushort* __restrict__ wto) {
  const int id = blockIdx.x;
  if (id < 512) {
    ln_x_body(x, ln_xg, ln_xb, xn, xnbf, id);
  } else if (id < 1536) {
    ln_y_body(y, ln_yg, ln_yb, ynbf, id - 512);
  } else {
    const int r = id - 1536;                 // 0..127
    const int z = r >> 5, rem = r & 31;
    const int bx = rem & 7, by = rem >> 3;
    if (z < 3) {
      const float* W = (z == 0) ? Wq : (z == 1) ? Wk : Wv;
      ushort* Wt = (z == 0) ? wtq : (z == 1) ? wtk : wtv;
      wprep_body(W, Wt, 256, 512, bx, by);
    } else {
      wprep_body(Wo, wto, 512, 256, bx & 3, by * 2 + (bx >> 2));
    }
  }
}

// ---------------------------------------------------------------------------
// bf16 MFMA GEMM body: C[M][N] = A[M][K] @ Bt[N][K]^T, 128x128 tile, BK=64,
// 4 waves (2x2), each wave 64x64. global_load_lds staging, rule-#21 swizzle.
// Optional vt_out: write C transposed per-head ([b*h][d][m]).
// ---------------------------------------------------------------------------
template <bool F32_RES_OUT>
static __device__ __forceinline__ void gemm_body(
    const ushort* __restrict__ A, const ushort* __restrict__ Bt,
    const float* __restrict__ bias, const float* __restrict__ res,
    void* __restrict__ Cout, ushort* __restrict__ vt_out,
    int M, int N, int K, float scale, int m0, int n0) {
  __shared__ ushort As[128 * 64];   // linear, 16 KiB
  __shared__ ushort Bs[128 * 64];
  const int t = threadIdx.x;
  const int l = t & 63, w = t >> 6;
  const int lq = l & 15, lg = l >> 4;
  const int wr = w >> 1, wc = w & 1;
  f32x4 acc[4][4];
  #pragma unroll
  for (int mt = 0; mt < 4; ++mt)
    #pragma unroll
    for (int nt = 0; nt < 4; ++nt)
      #pragma unroll
      for (int e = 0; e < 4; ++e) acc[mt][nt][e] = 0.f;
  const int srow = w * 8 + (l >> 3);
  const int scol = ((l & 7) ^ (l >> 3)) * 8;
  const ushort* pA = A + (size_t)(m0 + srow) * K + scol;
  const ushort* pB = Bt + (size_t)(n0 + srow) * K + scol;
  const int dbase = w * 512;               // shorts (wave chunk base)
  for (int k0 = 0; k0 < K; k0 += 64) {
    if (k0) __syncthreads();               // prior reads done before overwrite
    #pragma unroll
    for (int i = 0; i < 4; ++i) {
      gload16(pA + (size_t)(i * 32) * K + k0, &As[i * 2048 + dbase]);
      gload16(pB + (size_t)(i * 32) * K + k0, &Bs[i * 2048 + dbase]);
    }
    __syncthreads();                       // drains vmcnt -> tile visible
    #pragma unroll
    for (int ks = 0; ks < 2; ++ks) {
      bf16x8 af[4], bfr[4];
      #pragma unroll
      for (int mt = 0; mt < 4; ++mt) {
        const int R = wr * 64 + mt * 16 + lq;
        af[mt] = *(const bf16x8*)(
            &As[R * 64 + ((ks * 32 + lg * 8) ^ ((R & 7) * 8))]);
      }
      #pragma unroll
      for (int nt = 0; nt < 4; ++nt) {
        const int R = wc * 64 + nt * 16 + lq;
        bfr[nt] = *(const bf16x8*)(
            &Bs[R * 64 + ((ks * 32 + lg * 8) ^ ((R & 7) * 8))]);
      }
      #pragma unroll
      for (int mt = 0; mt < 4; ++mt)
        #pragma unroll
        for (int nt = 0; nt < 4; ++nt)
          acc[mt][nt] = __builtin_amdgcn_mfma_f32_16x16x32_bf16(
              af[mt], bfr[nt], acc[mt][nt], 0, 0, 0);
    }
  }
  #pragma unroll
  for (int nt = 0; nt < 4; ++nt) {
    const int colc = n0 + wc * 64 + nt * 16 + lq;
    const float bcol = bias ? bias[colc] : 0.f;
    #pragma unroll
    for (int mt = 0; mt < 4; ++mt) {
      #pragma unroll
      for (int i = 0; i < 4; ++i) {
        const size_t row = (size_t)(m0 + wr * 64 + mt * 16 + lg * 4 + i);
        float v = acc[mt][nt][i] * scale + bcol;
        if (vt_out) {
          // transposed per-head: vt[(bi*8+h)*64 + d][m], h=colc>>6, d=colc&63
          vt_out[(size_t)((((row >> 10) * 8 + (colc >> 6)) << 6) + (colc & 63)) * MCTX
                 + (row & (MCTX - 1))] = f2bf(v);
        } else if (F32_RES_OUT) {
          ((float*)Cout)[row * N + colc] = v + res[row * N + colc];
        } else {
          ((ushort*)Cout)[row * N + colc] = f2bf(v);
        }
      }
    }
  }
}

// ---------------------------------------------------------------------------
// MERGED PROJECTIONS: Q (512) + K (128) + V (128, transposed-epilogue).
// ---------------------------------------------------------------------------
__global__ __launch_bounds__(256) void qkv_kernel(
    const ushort* __restrict__ xnbf, const ushort* __restrict__ ynbf,
    const ushort* __restrict__ wtq, const ushort* __restrict__ wtk,
    const ushort* __restrict__ wtv, const float* __restrict__ bv,
    ushort* __restrict__ qbf, ushort* __restrict__ kbf,
    ushort* __restrict__ vtb) {
  const int id = blockIdx.x;
  if (id < 512) {
    // q = (xn @ Wq) * 0.125 * log2(e)  (softmax runs in exp2 domain)
    gemm_body<false>(xnbf, wtq, nullptr, nullptr, qbf, nullptr,
                     16384, 512, 256, 0.1803368801111204f,
                     (id >> 2) * 128, (id & 3) * 128);
  } else if (id < 640) {
    const int i2 = id - 512;
    gemm_body<false>(ynbf, wtk, nullptr, nullptr, kbf, nullptr,
                     4096, 512, 256, 1.f, (i2 >> 2) * 128, (i2 & 3) * 128);
  } else {
    const int i2 = id - 640;
    gemm_body<false>(ynbf, wtv, bv, nullptr, nullptr, vtb,
                     4096, 512, 256, 1.f, (i2 >> 2) * 128, (i2 & 3) * 128);
  }
}

// ---------------------------------------------------------------------------
// AO GEMM + residual: out[16384][256] = ao @ Wo + bo + xn.  64x128 tile,
// BK=64, 4 waves (2x2), each wave 32x64 — 512 blocks = 2/CU (measured r12:
// non-attn tail −6.6 us vs the 128x128 1-block/CU version).
// ---------------------------------------------------------------------------
__global__ __launch_bounds__(256) void ao_gemm_kernel(
    const ushort* __restrict__ A, const ushort* __restrict__ Bt,
    const float* __restrict__ bias, const float* __restrict__ res,
    float* __restrict__ out) {
  __shared__ ushort As[64 * 64];    // 8 KiB
  __shared__ ushort Bs[128 * 64];   // 16 KiB
  const int t = threadIdx.x;
  const int l = t & 63, w = t >> 6;
  const int lq = l & 15, lg = l >> 4;
  const int wr = w >> 1, wc = w & 1;
  const int m0 = blockIdx.y * 64, n0 = blockIdx.x * 128;
  f32x4 acc[2][4];
  #pragma unroll
  for (int mt = 0; mt < 2; ++mt)
    #pragma unroll
    for (int nt = 0; nt < 4; ++nt)
      #pragma unroll
      for (int e = 0; e < 4; ++e) acc[mt][nt][e] = 0.f;
  const int srow = w * 8 + (l >> 3);
  const int scol = ((l & 7) ^ (l >> 3)) * 8;
  const ushort* pA = A + (size_t)(m0 + srow) * INNER + scol;
  const ushort* pB = Bt + (size_t)(n0 + srow) * INNER + scol;
  const int dbase = w * 512;
  for (int k0 = 0; k0 < INNER; k0 += 64) {
    if (k0) __syncthreads();
    #pragma unroll
    for (int i = 0; i < 2; ++i)
      gload16(pA + (size_t)(i * 32) * INNER + k0, &As[i * 2048 + dbase]);
    #pragma unroll
    for (int i = 0; i < 4; ++i)
      gload16(pB + (size_t)(i * 32) * INNER + k0, &Bs[i * 2048 + dbase]);
    __syncthreads();
    #pragma unroll
    for (int ks = 0; ks < 2; ++ks) {
      bf16x8 af[2], bfr[4];
      #pragma unroll
      for (int mt = 0; mt < 2; ++mt) {
        const int R = wr * 32 + mt * 16 + lq;
        af[mt] = *(const bf16x8*)(
            &As[R * 64 + ((ks * 32 + lg * 8) ^ ((R & 7) * 8))]);
      }
      #pragma unroll
      for (int nt = 0; nt < 4; ++nt) {
        const int R = wc * 64 + nt * 16 + lq;
        bfr[nt] = *(const bf16x8*)(
            &Bs[R * 64 + ((ks * 32 + lg * 8) ^ ((R & 7) * 8))]);
      }
      #pragma unroll
      for (int mt = 0; mt < 2; ++mt)
        #pragma unroll
        for (int nt = 0; nt < 4; ++nt)
          acc[mt][nt] = __builtin_amdgcn_mfma_f32_16x16x32_bf16(
              af[mt], bfr[nt], acc[mt][nt], 0, 0, 0);
    }
  }
  #pragma unroll
  for (int nt = 0; nt < 4; ++nt) {
    const int colc = n0 + wc * 64 + nt * 16 + lq;
    const float bcol = bias[colc];
    #pragma unroll
    for (int mt = 0; mt < 2; ++mt) {
      #pragma unroll
      for (int i = 0; i < 4; ++i) {
        const size_t row = (size_t)(m0 + wr * 32 + mt * 16 + lg * 4 + i);
        out[row * CDIM + colc] = acc[mt][nt][i] + bcol + res[row * CDIM + colc];
      }
    }
  }
}

// ---------------------------------------------------------------------------
// Flash attention, bf16 MFMA, 32x32 tiles + in-register P via permlane swap.
// r11 version VERBATIM — the measured optimum (56.5-58.5 us across r10-r12).
// q:[b*n][512] pre-scaled 0.125*log2e; k:[b*m][512]; vt:[b*h][64 d][1024 m].
// Block: (b,h) x 256 q-rows; 8 waves x 32 q-rows (one 32x32 group per wave).
// QK^T: St[2] = mfma_32x32x16(K-frag, Q-frag) over d=64 (8 mfma/tile).
// C-layout (m74/m101): col=q=lane&31, row=key=(reg&3)+8*(reg>>2)+4*(lane>>5).
// Softmax fully in-lane (32 vals) + one shfl_xor(32); exp2 domain; defer-max.
// P -> PV A-frags IN REGISTERS via v_permlane32_swap_b32 (frag=[Sa,Sb,Da,Db]
// valid for BOTH lane halves). PV: 8 mfma_32x32x16.
// LEDGER (do not revisit): 4-wave blocks -13% (r5); gload_lds K/V in attn
// -13% (r5); min-waves>4 at 512thr spills (r3); K=16 PV -7% (r8); intra-tile
// reorder flat (r4); 16x16+LDS-P = 61-62us (r7/r9); 2-group/wave at (512,2)
// -13% (r12: occupancy 20%, latency-hiding loss > LDS savings).
// ---------------------------------------------------------------------------
__global__ __launch_bounds__(512, 4) void attn_mfma(
    const ushort* __restrict__ q, const ushort* __restrict__ k,
    const ushort* __restrict__ vt, ushort* __restrict__ ao) {
  // XCD-aware swizzle (bijective: 512 = 8 * 64)
  const int bid = blockIdx.x + 16 * (blockIdx.y + 8 * blockIdx.z);
  const int swz = (bid & 7) * 64 + (bid >> 3);
  const int bi = swz >> 7;
  const int h = (swz >> 4) & 7;
  const int n0 = (swz & 15) * 256;
  const int tile0 = (bid & 3) << 2;        // phase stagger: 0,4,8,12
  __shared__ ushort Ks[2][64 * 64];
  __shared__ ushort Vs[2][64 * 64];
  const int t = threadIdx.x;
  const int l = t & 63, w = t >> 6;
  const int lq32 = l & 31, hi = l >> 5;

  // Q fragments (B operand of QK: B[k=d][col=q], k=(lane>>5)*8+e per d-step)
  bf16x8 bq[4];
  {
    const size_t qrow = (size_t)(bi * HW + n0 + w * 32 + lq32);
    #pragma unroll
    for (int ds = 0; ds < 4; ++ds)
      bq[ds] = *(const bf16x8*)(q + qrow * INNER + h * DHEAD + ds * 16 + hi * 8);
  }

  float m_run = -1e30f, l_run = 0.f;
  f32x16 oacc[2];                           // O[q][d], d-tiles of 32
  #pragma unroll
  for (int dt = 0; dt < 2; ++dt)
    #pragma unroll
    for (int e = 0; e < 16; ++e) oacc[dt][e] = 0.f;

  // staging: 64x64 bf16 tile = 512 uint4; 512 threads -> 1 uint4 each per tile
  const int rr = t >> 3, cc = (t & 7) * 8;
  const ushort* kptr = k + (size_t)(bi * MCTX + rr) * INNER + h * DHEAD + cc;
  const ushort* vptr = vt + (size_t)((bi * HEADS + h) * 64 + rr) * MCTX + cc;
  const int sidx = (rr * 64 + cc) ^ ((rr & 7) << 3);

  {  // stage first tile (tile0) into buffer 0
    const int ms = tile0 << 6;
    uint4 k0v = *(const uint4*)(kptr + (size_t)ms * INNER);
    uint4 v0v = *(const uint4*)(vptr + ms);
    *(uint4*)(&Ks[0][sidx]) = k0v;
    *(uint4*)(&Vs[0][sidx]) = v0v;
  }
  __syncthreads();

  #pragma unroll 2
  for (int it = 0; it < 16; ++it) {
    const int buf = it & 1;
    const bool more = (it + 1) < 16;
    const int mnext = ((tile0 + it + 1) & 15) << 6;
    uint4 kpre{}, vpre{};
    if (more) {  // prefetch next tile; staged to LDS after softmax
      kpre = *(const uint4*)(kptr + (size_t)mnext * INNER);
      vpre = *(const uint4*)(vptr + mnext);
    }
    // QK^T: St[kt][key=32kt+row][q=lane&31] over d=64, A=K-frag from Ks
    f32x16 sc[2];
    #pragma unroll
    for (int kt = 0; kt < 2; ++kt)
      #pragma unroll
      for (int e = 0; e < 16; ++e) sc[kt][e] = 0.f;
    __builtin_amdgcn_s_setprio(1);
    #pragma unroll
    for (int kt = 0; kt < 2; ++kt) {
      #pragma unroll
      for (int ds = 0; ds < 4; ++ds) {
        const int krow = kt * 32 + lq32;
        bf16x8 ak = *(const bf16x8*)(
            &Ks[buf][(krow * 64 + ds * 16 + hi * 8) ^ ((krow & 7) << 3)]);
        sc[kt] = __builtin_amdgcn_mfma_f32_32x32x16_bf16(ak, bq[ds], sc[kt], 0, 0, 0);
      }
    }
    __builtin_amdgcn_s_setprio(0);
    // ---- softmax (q = lane&31; lanes l, l+32 hold complementary keys) ----
    f32x16 mx;
    #pragma unroll
    for (int e = 0; e < 16; ++e) mx[e] = fmaxf(sc[0][e], sc[1][e]);
    #pragma unroll
    for (int e = 0; e < 8; ++e) mx[e] = fmaxf(mx[e], mx[e + 8]);
    #pragma unroll
    for (int e = 0; e < 4; ++e) mx[e] = fmaxf(mx[e], mx[e + 4]);
    float mloc = fmaxf(fmaxf(mx[0], mx[1]), fmaxf(mx[2], mx[3]));
    mloc = fmaxf(mloc, __shfl_xor(mloc, 32));
    // defer-max: only rescale when some q-row's max grew by > 8 (log2 units)
    if (!__all((int)(mloc - m_run <= 8.f))) {
      const float mnew = fmaxf(m_run, mloc);
      const float corr = __builtin_amdgcn_exp2f(m_run - mnew);
      l_run *= corr;
      m_run = mnew;
      #pragma unroll
      for (int r = 0; r < 16; ++r) {
        const int qrow = (r & 3) + 8 * (r >> 2) + 4 * hi;
        float ci = __shfl(corr, qrow);
        oacc[0][r] *= ci; oacc[1][r] *= ci;
      }
    }
    #pragma unroll
    for (int kt = 0; kt < 2; ++kt)
      #pragma unroll
      for (int e = 0; e < 16; ++e)
        sc[kt][e] = __builtin_amdgcn_exp2f(sc[kt][e] - m_run);
    f32x16 s16;
    #pragma unroll
    for (int e = 0; e < 16; ++e) s16[e] = sc[0][e] + sc[1][e];
    #pragma unroll
    for (int e = 0; e < 8; ++e) s16[e] += s16[e + 8];
    #pragma unroll
    for (int e = 0; e < 4; ++e) s16[e] += s16[e + 4];
    float psum = (s16[0] + s16[1]) + (s16[2] + s16[3]);
    psum += __shfl_xor(psum, 32);
    l_run += psum;
    // ---- P -> PV A-frags in registers (pack + permlane32_swap) ----
    bf16x8 pafr[4];
    #pragma unroll
    for (int kt = 0; kt < 2; ++kt) {
      uint wa[4], wb[4];
      #pragma unroll
      for (int r4 = 0; r4 < 4; ++r4) {
        wa[r4] = (uint)f2bf(sc[kt][4 * r4]) | ((uint)f2bf(sc[kt][4 * r4 + 1]) << 16);
        wb[r4] = (uint)f2bf(sc[kt][4 * r4 + 2]) | ((uint)f2bf(sc[kt][4 * r4 + 3]) << 16);
      }
      #pragma unroll
      for (int p2 = 0; p2 < 2; ++p2) {
        uint Sa = wa[2 * p2], Da = wa[2 * p2 + 1];
        uint Sb = wb[2 * p2], Db = wb[2 * p2 + 1];
        asm volatile("v_permlane32_swap_b32 %0, %1" : "+v"(Da), "+v"(Sa));
        asm volatile("v_permlane32_swap_b32 %0, %1" : "+v"(Db), "+v"(Sb));
        uint4 fr;
        fr.x = Sa; fr.y = Sb; fr.z = Da; fr.w = Db;
        pafr[kt * 2 + p2] = *reinterpret_cast<bf16x8*>(&fr);
      }
    }
    // stage next tile into the other buffer (safe: buf^1 last read before
    // the previous barrier); drains during PV
    if (more) {
      *(uint4*)(&Ks[buf ^ 1][sidx]) = kpre;
      *(uint4*)(&Vs[buf ^ 1][sidx]) = vpre;
    }
    // ---- PV: O[q][d] += P @ V, B-frag = V[key][d] from Vs[d][key] ----
    __builtin_amdgcn_s_setprio(1);
    #pragma unroll
    for (int dt = 0; dt < 2; ++dt) {
      const int vrow = dt * 32 + lq32;
      #pragma unroll
      for (int kt16 = 0; kt16 < 4; ++kt16) {
        bf16x8 vb = *(const bf16x8*)(
            &Vs[buf][(vrow * 64 + kt16 * 16 + hi * 8) ^ ((vrow & 7) << 3)]);
        oacc[dt] = __builtin_amdgcn_mfma_f32_32x32x16_bf16(pafr[kt16], vb, oacc[dt], 0, 0, 0);
      }
    }
    __builtin_amdgcn_s_setprio(0);
    __syncthreads();
  }
  const float rl = 1.f / l_run;
  #pragma unroll
  for (int r = 0; r < 16; ++r) {
    const int qrow = (r & 3) + 8 * (r >> 2) + 4 * hi;
    float li = __shfl(rl, qrow);
    const size_t row = (size_t)(bi * HW + n0 + w * 32 + qrow);
    ao[row * INNER + h * DHEAD + lq32] = f2bf(oacc[0][r] * li);
    ao[row * INNER + h * DHEAD + 32 + lq32] = f2bf(oacc[1][r] * li);
  }
}

// ---------------------------------------------------------------------------
extern "C" void kernel_launch(void* const* d_in, const int* in_sizes, int n_in,
                              void* d_out, int out_size, void* d_ws, size_t ws_size,
                              hipStream_t stream) {
  const float* x     = (const float*)d_in[0];
  const float* y     = (const float*)d_in[1];
  const float* ln_xg = (const float*)d_in[2];
  const float* ln_xb = (const float*)d_in[3];
  const float* ln_yg = (const float*)d_in[4];
  const float* ln_yb = (const float*)d_in[5];
  const float* Wq    = (const float*)d_in[6];
  const float* Wk    = (const float*)d_in[7];
  const float* Wv    = (const float*)d_in[8];
  const float* bv    = (const float*)d_in[9];
  const float* Wo    = (const float*)d_in[10];
  const float* bo    = (const float*)d_in[11];
  float* out = (float*)d_out;

  char* p = (char*)d_ws;
  float*  xn   = (float*)p;  p += (size_t)16384 * 256 * 4;
  ushort* xnbf = (ushort*)p; p += (size_t)16384 * 256 * 2;
  ushort* ynbf = (ushort*)p; p += (size_t)4096 * 256 * 2;
  ushort* wtq  = (ushort*)p; p += (size_t)512 * 256 * 2;
  ushort* wtk  = (ushort*)p; p += (size_t)512 * 256 * 2;
  ushort* wtv  = (ushort*)p; p += (size_t)512 * 256 * 2;
  ushort* wto  = (ushort*)p; p += (size_t)256 * 512 * 2;
  ushort* qbf  = (ushort*)p; p += (size_t)16384 * 512 * 2;
  ushort* kbf  = (ushort*)p; p += (size_t)4096 * 512 * 2;
  ushort* vtb  = (ushort*)p; p += (size_t)4096 * 512 * 2;
  ushort* aobf = (ushort*)p; p += (size_t)16384 * 512 * 2;

  // 1) all preprocessing in one launch (ln_x first: longest)
  prep_kernel<<<dim3(512 + 1024 + 128), 256, 0, stream>>>(
      x, ln_xg, ln_xb, xn, xnbf, y, ln_yg, ln_yb, ynbf,
      Wq, Wk, Wv, Wo, wtq, wtk, wtv, wto);
  // 2) Q + K + V projections in one launch (V written transposed per-head)
  qkv_kernel<<<dim3(768), 256, 0, stream>>>(
      xnbf, ynbf, wtq, wtk, wtv, bv, qbf, kbf, vtb);
  // 3) attention (256 q-rows/block, 1 group/wave — r11 optimum)
  attn_mfma<<<dim3(HW / 256, HEADS, BATCH), 512, 0, stream>>>(qbf, kbf, vtb, aobf);
  // 4) out = ao @ Wo + bo + xn  (64x128 tiles -> 512 blocks, 2/CU)
  ao_gemm_kernel<<<dim3(2, 256), 256, 0, stream>>>(aobf, wto, bo, xn, out);
}